// Round 11
// baseline (44.027 us; speedup 1.0000x reference)
//
#include <hip/hip_runtime.h>
#include <hip/hip_bf16.h>

#define K_CLS 64
#define DIM   256
#define TPB1  512      // 8 waves; wave w owns dims [32w, 32w+32)
#define MAXROWS 2048
#define NBLK_TGT 512   // 2 blocks/CU for doubled memory-level parallelism

typedef __attribute__((ext_vector_type(8)))  short short8;
typedef __attribute__((ext_vector_type(16))) float f32x16;
typedef __attribute__((ext_vector_type(4)))  unsigned int uint4v;

__device__ inline float bf2f(unsigned short h) {
    return __uint_as_float(((unsigned)h) << 16);
}
__device__ inline unsigned short f2bf(float x) {  // f32 -> bf16 RNE (epilogue only)
    unsigned u = __float_as_uint(x);
    u += 0x7FFFu + ((u >> 16) & 1u);
    return (unsigned short)(u >> 16);
}
__device__ inline unsigned int pkbf(float lo, float hi) {  // packed v_cvt_pk_bf16_f32
    float2 p; p.x = lo; p.y = hi;
    __hip_bfloat162 h = __float22bfloat162_rn(p);
    unsigned int r;
    __builtin_memcpy(&r, &h, sizeof(r));
    return r;
}

// ---------------------------------------------------------------------------
// Pass 1: per-block partial segment-sums via one-hot MFMA (bf16 partials out).
//   psum[blk][k][d] = sum_{r in blk, c[r]==k} z[r][d]
//   psq [blk][k][d] = sum z[r][d]^2          pcnt[k][blk] = count
// 2 independent blocks/CU (launch_bounds(512,4) caps VGPR at 128) double the
// in-flight load bytes per SIMD without any extra barriers — the MLP needed
// to cover ~900cy HBM latency at 24.6 B/cy/CU.
// Block 0 zeroes the var slots of `out` for pass 2's atomics.
// ---------------------------------------------------------------------------
__global__ __launch_bounds__(TPB1, 4) void fstat_p1(
    const float* __restrict__ z, const int* __restrict__ c,
    unsigned short* __restrict__ psum, unsigned short* __restrict__ psq,
    float* __restrict__ pcnt, float* __restrict__ out,
    int rows_per_blk, int nblk)
{
    __shared__ __align__(16) int cs[MAXROWS];
    __shared__ float lcnt[K_CLS];
    const int t   = threadIdx.x;
    const int blk = blockIdx.x;
    const int rb0 = blk * rows_per_blk;

    if (blk == 0 && t < K_CLS) out[K_CLS * DIM + t] = 0.f;   // var accumulators

    if (t < K_CLS) lcnt[t] = 0.f;
    __syncthreads();
    for (int r = t; r < rows_per_blk; r += TPB1) {
        int cv = c[rb0 + r];
        cs[r] = cv;
        atomicAdd(&lcnt[cv], 1.0f);
    }
    __syncthreads();

    const int wave = t >> 6;
    const int lane = t & 63;
    const int db   = wave * 32;         // this wave's dim base
    const int half = lane >> 5;         // k-half: rows +0..7 vs +8..15
    const int ln   = lane & 31;
    const int ln32 = ln + 32;

    f32x16 aS0 = {}; f32x16 aS1 = {}; f32x16 aQ0 = {}; f32x16 aQ1 = {};

    const int nsteps = rows_per_blk >> 4;
    const size_t zo0 = (size_t)(rb0 + half * 8) * DIM + db + ln;

    float v[8];
    #pragma unroll
    for (int i = 0; i < 8; ++i) v[i] = z[zo0 + (size_t)i * DIM];

    for (int step = 0; step < nsteps; ++step) {
        float vn[8];
        if (step + 1 < nsteps) {
            const size_t zo = zo0 + (size_t)(step + 1) * 16 * DIM;
            #pragma unroll
            for (int i = 0; i < 8; ++i) vn[i] = z[zo + (size_t)i * DIM];
        }
        const int rb = step * 16 + half * 8;
        int4 c0 = *reinterpret_cast<const int4*>(&cs[rb]);
        int4 c1 = *reinterpret_cast<const int4*>(&cs[rb + 4]);
        int cl[8] = {c0.x, c0.y, c0.z, c0.w, c1.x, c1.y, c1.z, c1.w};

        uint4v ua0, ua1, ubz, ubq;
        #pragma unroll
        for (int i = 0; i < 4; ++i) {
            int l0 = cl[2 * i], l1 = cl[2 * i + 1];
            ua0[i] = (l0 == ln   ? 0x00003F80u : 0u) | (l1 == ln   ? 0x3F800000u : 0u);
            ua1[i] = (l0 == ln32 ? 0x00003F80u : 0u) | (l1 == ln32 ? 0x3F800000u : 0u);
            float v0 = v[2 * i], v1 = v[2 * i + 1];
            ubz[i] = pkbf(v0, v1);
            ubq[i] = pkbf(v0 * v0, v1 * v1);
        }
        short8 A0 = __builtin_bit_cast(short8, ua0);
        short8 A1 = __builtin_bit_cast(short8, ua1);
        short8 Bz = __builtin_bit_cast(short8, ubz);
        short8 Bq = __builtin_bit_cast(short8, ubq);

        aS0 = __builtin_amdgcn_mfma_f32_32x32x16_bf16(A0, Bz, aS0, 0, 0, 0);
        aS1 = __builtin_amdgcn_mfma_f32_32x32x16_bf16(A1, Bz, aS1, 0, 0, 0);
        aQ0 = __builtin_amdgcn_mfma_f32_32x32x16_bf16(A0, Bq, aQ0, 0, 0, 0);
        aQ1 = __builtin_amdgcn_mfma_f32_32x32x16_bf16(A1, Bq, aQ1, 0, 0, 0);
        if (step + 1 < nsteps) {
            #pragma unroll
            for (int i = 0; i < 8; ++i) v[i] = vn[i];
        }
    }

    // ---- bf16 partial writes (coalesced 64B segments per 32-lane group) ----
    unsigned short* ps = psum + (size_t)blk * K_CLS * DIM;
    unsigned short* pq = psq  + (size_t)blk * K_CLS * DIM;
    #pragma unroll
    for (int r = 0; r < 16; ++r) {
        int row = (r & 3) + 8 * (r >> 2) + 4 * half;     // verified C/D mapping
        size_t o0 = (size_t)row * DIM + db + ln;
        size_t o1 = (size_t)(row + 32) * DIM + db + ln;
        ps[o0] = f2bf(aS0[r]); ps[o1] = f2bf(aS1[r]);
        pq[o0] = f2bf(aQ0[r]); pq[o1] = f2bf(aQ1[r]);
    }
    __syncthreads();
    if (t < K_CLS) pcnt[(size_t)t * nblk + blk] = lcnt[t];
}

// ---------------------------------------------------------------------------
// Pass 2: block = (class k, dim-quarter q). Reduce nblk partials; write
// centroids; accumulate this quarter's var contribution
//   sum_{d in q} (qu_d/cnt - mu_d^2)
// into out[K*DIM + k] via device atomics (slots pre-zeroed by pass 1).
// ---------------------------------------------------------------------------
__global__ __launch_bounds__(1024) void fstat_p2(
    const unsigned short* __restrict__ psum, const unsigned short* __restrict__ psq,
    const float* __restrict__ pcnt, float* __restrict__ out, int nblk)
{
    const int k  = blockIdx.x >> 2;
    const int q  = blockIdx.x & 3;
    const int t  = threadIdx.x;
    const int d  = t & 63;
    const int sg = t >> 6;

    __shared__ float redS[16][64];
    __shared__ float redQ[16][64];
    __shared__ float redC[512];
    __shared__ float sh_cnt;

    if (t < 512) {
        float cp = 0.f;
        for (int b = t; b < nblk; b += 512) cp += pcnt[(size_t)k * nblk + b];
        redC[t] = cp;
    }
    __syncthreads();
    if (t < 64) {
        float cp = 0.f;
        #pragma unroll
        for (int j = 0; j < 8; ++j) cp += redC[t + 64 * j];
        #pragma unroll
        for (int off = 32; off > 0; off >>= 1) cp += __shfl_down(cp, off);
        if (t == 0) sh_cnt = cp;
    }

    float s = 0.f, qq = 0.f;
    for (int b = sg; b < nblk; b += 16) {
        size_t o = ((size_t)b * K_CLS + k) * DIM + q * 64 + d;
        s  += bf2f(psum[o]);
        qq += bf2f(psq[o]);
    }
    redS[sg][d] = s;
    redQ[sg][d] = qq;
    __syncthreads();

    if (t < 64) {
        float su = 0.f, qu = 0.f;
        #pragma unroll
        for (int i = 0; i < 16; ++i) { su += redS[i][t]; qu += redQ[i][t]; }
        float cnt = fmaxf(sh_cnt, 1.f);
        float mu  = su / cnt;
        out[(size_t)k * DIM + q * 64 + t] = mu;
        float vp = qu / cnt - mu * mu;          // per-dim var contribution
        #pragma unroll
        for (int off = 32; off > 0; off >>= 1) vp += __shfl_down(vp, off);
        if (t == 0) atomicAdd(&out[K_CLS * DIM + k], vp);
    }
}

extern "C" void kernel_launch(void* const* d_in, const int* in_sizes, int n_in,
                              void* d_out, int out_size, void* d_ws, size_t ws_size,
                              hipStream_t stream)
{
    const float* z = (const float*)d_in[0];
    const int*   c = (const int*)d_in[1];
    float* out = (float*)d_out;
    const int N = in_sizes[1];   // rows = B*S

    auto need = [](int nb) {
        return 2 * (size_t)nb * K_CLS * DIM * sizeof(unsigned short)  // psum+psq
             + (size_t)K_CLS * nb * sizeof(float);                    // pcnt
    };
    int nblk = NBLK_TGT;
    while (nblk > 64 &&
           (N % nblk != 0 || (N / nblk) % 16 != 0 || (N / nblk) > MAXROWS ||
            need(nblk) > ws_size))
        nblk >>= 1;

    const int rows_per_blk = N / nblk;

    unsigned short* psum = (unsigned short*)d_ws;
    unsigned short* psq  = psum + (size_t)nblk * K_CLS * DIM;
    float* pcnt = (float*)(psq + (size_t)nblk * K_CLS * DIM);

    fstat_p1<<<nblk, TPB1, 0, stream>>>(z, c, psum, psq, pcnt, out, rows_per_blk, nblk);
    fstat_p2<<<K_CLS * 4, 1024, 0, stream>>>(psum, psq, pcnt, out, nblk);
}

// Round 12
// 36.191 us; speedup vs baseline: 1.2165x; 1.2165x over previous
//
#include <hip/hip_runtime.h>
#include <hip/hip_bf16.h>

#define K_CLS 64
#define DIM   256
#define TPB1  512      // 8 waves; wave w owns dims [32w, 32w+32)
#define MAXROWS 2048

typedef __attribute__((ext_vector_type(8)))  short short8;
typedef __attribute__((ext_vector_type(16))) float f32x16;
typedef __attribute__((ext_vector_type(4)))  unsigned int uint4v;

__device__ inline float bf2f(unsigned short h) {
    return __uint_as_float(((unsigned)h) << 16);
}
__device__ inline unsigned short f2bf(float x) {  // f32 -> bf16 RNE (epilogue only)
    unsigned u = __float_as_uint(x);
    u += 0x7FFFu + ((u >> 16) & 1u);
    return (unsigned short)(u >> 16);
}
__device__ inline unsigned int pkbf(float lo, float hi) {  // packed v_cvt_pk_bf16_f32
    float2 p; p.x = lo; p.y = hi;
    __hip_bfloat162 h = __float22bfloat162_rn(p);
    unsigned int r;
    __builtin_memcpy(&r, &h, sizeof(r));
    return r;
}

// ---------------------------------------------------------------------------
// Pass 1: per-block partial segment-sums via one-hot MFMA (bf16 partials out).
//   psum[blk][k][d] = sum_{r in blk, c[r]==k} z[r][d]
//   psq [blk][k][d] = sum z[r][d]^2          pcnt[k][blk] = count
// Block 0 additionally zeroes the var slots of `out` so pass 2 can
// accumulate into them with atomics (all p1 blocks retire before p2 runs).
// ---------------------------------------------------------------------------
__global__ __launch_bounds__(TPB1) void fstat_p1(
    const float* __restrict__ z, const int* __restrict__ c,
    unsigned short* __restrict__ psum, unsigned short* __restrict__ psq,
    float* __restrict__ pcnt, float* __restrict__ out,
    int rows_per_blk, int nblk)
{
    __shared__ __align__(16) int cs[MAXROWS];
    __shared__ float lcnt[K_CLS];
    const int t   = threadIdx.x;
    const int blk = blockIdx.x;
    const int rb0 = blk * rows_per_blk;

    if (blk == 0 && t < K_CLS) out[K_CLS * DIM + t] = 0.f;   // var accumulators

    if (t < K_CLS) lcnt[t] = 0.f;
    __syncthreads();
    for (int r = t; r < rows_per_blk; r += TPB1) {
        int cv = c[rb0 + r];
        cs[r] = cv;
        atomicAdd(&lcnt[cv], 1.0f);
    }
    __syncthreads();

    const int wave = t >> 6;
    const int lane = t & 63;
    const int db   = wave * 32;         // this wave's dim base
    const int half = lane >> 5;         // k-half: rows +0..7 vs +8..15
    const int ln   = lane & 31;
    const int ln32 = ln + 32;

    f32x16 aS0 = {}; f32x16 aS1 = {}; f32x16 aQ0 = {}; f32x16 aQ1 = {};

    const int nsteps = rows_per_blk >> 4;
    const size_t zo0 = (size_t)(rb0 + half * 8) * DIM + db + ln;

    float v[8];
    #pragma unroll
    for (int i = 0; i < 8; ++i) v[i] = z[zo0 + (size_t)i * DIM];

    for (int step = 0; step < nsteps; ++step) {
        float vn[8];
        if (step + 1 < nsteps) {
            const size_t zo = zo0 + (size_t)(step + 1) * 16 * DIM;
            #pragma unroll
            for (int i = 0; i < 8; ++i) vn[i] = z[zo + (size_t)i * DIM];
        }
        const int rb = step * 16 + half * 8;
        int4 c0 = *reinterpret_cast<const int4*>(&cs[rb]);
        int4 c1 = *reinterpret_cast<const int4*>(&cs[rb + 4]);
        int cl[8] = {c0.x, c0.y, c0.z, c0.w, c1.x, c1.y, c1.z, c1.w};

        uint4v ua0, ua1, ubz, ubq;
        #pragma unroll
        for (int i = 0; i < 4; ++i) {
            int l0 = cl[2 * i], l1 = cl[2 * i + 1];
            ua0[i] = (l0 == ln   ? 0x00003F80u : 0u) | (l1 == ln   ? 0x3F800000u : 0u);
            ua1[i] = (l0 == ln32 ? 0x00003F80u : 0u) | (l1 == ln32 ? 0x3F800000u : 0u);
            float v0 = v[2 * i], v1 = v[2 * i + 1];
            ubz[i] = pkbf(v0, v1);
            ubq[i] = pkbf(v0 * v0, v1 * v1);
        }
        short8 A0 = __builtin_bit_cast(short8, ua0);
        short8 A1 = __builtin_bit_cast(short8, ua1);
        short8 Bz = __builtin_bit_cast(short8, ubz);
        short8 Bq = __builtin_bit_cast(short8, ubq);

        aS0 = __builtin_amdgcn_mfma_f32_32x32x16_bf16(A0, Bz, aS0, 0, 0, 0);
        aS1 = __builtin_amdgcn_mfma_f32_32x32x16_bf16(A1, Bz, aS1, 0, 0, 0);
        aQ0 = __builtin_amdgcn_mfma_f32_32x32x16_bf16(A0, Bq, aQ0, 0, 0, 0);
        aQ1 = __builtin_amdgcn_mfma_f32_32x32x16_bf16(A1, Bq, aQ1, 0, 0, 0);
        if (step + 1 < nsteps) {
            #pragma unroll
            for (int i = 0; i < 8; ++i) v[i] = vn[i];
        }
    }

    // ---- bf16 partial writes (coalesced 64B segments per 32-lane group) ----
    unsigned short* ps = psum + (size_t)blk * K_CLS * DIM;
    unsigned short* pq = psq  + (size_t)blk * K_CLS * DIM;
    #pragma unroll
    for (int r = 0; r < 16; ++r) {
        int row = (r & 3) + 8 * (r >> 2) + 4 * half;     // verified C/D mapping
        size_t o0 = (size_t)row * DIM + db + ln;
        size_t o1 = (size_t)(row + 32) * DIM + db + ln;
        ps[o0] = f2bf(aS0[r]); ps[o1] = f2bf(aS1[r]);
        pq[o0] = f2bf(aQ0[r]); pq[o1] = f2bf(aQ1[r]);
    }
    __syncthreads();
    if (t < K_CLS) pcnt[(size_t)t * nblk + blk] = lcnt[t];
}

// ---------------------------------------------------------------------------
// Pass 2: block = (class k, dim-quarter q). Reduce nblk partials; write
// centroids; accumulate this quarter's var contribution
//   sum_{d in q} (qu_d/cnt - mu_d^2)
// into out[K*DIM + k] via device atomics (slots pre-zeroed by pass 1).
// ---------------------------------------------------------------------------
__global__ __launch_bounds__(1024) void fstat_p2(
    const unsigned short* __restrict__ psum, const unsigned short* __restrict__ psq,
    const float* __restrict__ pcnt, float* __restrict__ out, int nblk)
{
    const int k  = blockIdx.x >> 2;
    const int q  = blockIdx.x & 3;
    const int t  = threadIdx.x;
    const int d  = t & 63;
    const int sg = t >> 6;

    __shared__ float redS[16][64];
    __shared__ float redQ[16][64];
    __shared__ float redC[256];
    __shared__ float sh_cnt;

    if (t < 256) redC[t] = (t < nblk) ? pcnt[(size_t)k * nblk + t] : 0.f;
    __syncthreads();
    if (t < 64) {
        float cp = redC[t] + redC[t + 64] + redC[t + 128] + redC[t + 192];
        #pragma unroll
        for (int off = 32; off > 0; off >>= 1) cp += __shfl_down(cp, off);
        if (t == 0) sh_cnt = cp;
    }

    float s = 0.f, qq = 0.f;
    for (int b = sg; b < nblk; b += 16) {
        size_t o = ((size_t)b * K_CLS + k) * DIM + q * 64 + d;
        s  += bf2f(psum[o]);
        qq += bf2f(psq[o]);
    }
    redS[sg][d] = s;
    redQ[sg][d] = qq;
    __syncthreads();

    if (t < 64) {
        float su = 0.f, qu = 0.f;
        #pragma unroll
        for (int i = 0; i < 16; ++i) { su += redS[i][t]; qu += redQ[i][t]; }
        float cnt = fmaxf(sh_cnt, 1.f);
        float mu  = su / cnt;
        out[(size_t)k * DIM + q * 64 + t] = mu;
        float vp = qu / cnt - mu * mu;          // per-dim var contribution
        #pragma unroll
        for (int off = 32; off > 0; off >>= 1) vp += __shfl_down(vp, off);
        if (t == 0) atomicAdd(&out[K_CLS * DIM + k], vp);
    }
}

extern "C" void kernel_launch(void* const* d_in, const int* in_sizes, int n_in,
                              void* d_out, int out_size, void* d_ws, size_t ws_size,
                              hipStream_t stream)
{
    const float* z = (const float*)d_in[0];
    const int*   c = (const int*)d_in[1];
    float* out = (float*)d_out;
    const int N = in_sizes[1];   // rows = B*S

    auto need = [](int nb) {
        return 2 * (size_t)nb * K_CLS * DIM * sizeof(unsigned short)  // psum+psq
             + (size_t)K_CLS * nb * sizeof(float);                    // pcnt
    };
    int nblk = 256;
    while (nblk > 64 &&
           (N % nblk != 0 || (N / nblk) % 16 != 0 || (N / nblk) > MAXROWS ||
            need(nblk) > ws_size))
        nblk >>= 1;

    const int rows_per_blk = N / nblk;

    unsigned short* psum = (unsigned short*)d_ws;
    unsigned short* psq  = psum + (size_t)nblk * K_CLS * DIM;
    float* pcnt = (float*)(psq + (size_t)nblk * K_CLS * DIM);

    fstat_p1<<<nblk, TPB1, 0, stream>>>(z, c, psum, psq, pcnt, out, rows_per_blk, nblk);
    fstat_p2<<<K_CLS * 4, 1024, 0, stream>>>(psum, psq, pcnt, out, nblk);
}